// Round 1
// baseline (120.012 us; speedup 1.0000x reference)
//
#include <hip/hip_runtime.h>
#include <hip/hip_bf16.h>

// out[n] = bump( max_l min_f max_c |A[n,l,c] - B[c,f]| ),  bump(x)=sigmoid(10x)*sigmoid(-10x)
// N=64, L=512, F=2048.  A:(64,512,2) f32, B:(1,2,2048) f32, out:(64,1) f32.

#define NN 64
#define LL 512
#define FF 2048

__global__ __launch_bounds__(256) void psl_reduce_kernel(
    const float* __restrict__ A, const float* __restrict__ B,
    unsigned* __restrict__ ws) {
  const int wave = threadIdx.x >> 6;
  const int lane = threadIdx.x & 63;
  const int p    = blockIdx.x * 4 + wave;   // pair index: p = n*512 + l
  const int n    = p >> 9;

  // A[n,l,0..1] is contiguous: float2 at index p (wave-uniform broadcast load)
  const float2 a = ((const float2*)A)[p];
  const float* __restrict__ B0 = B;         // B[0,0,f]
  const float* __restrict__ B1 = B + FF;    // B[0,1,f]

  float m = 3.4e38f;
#pragma unroll
  for (int i = 0; i < FF / 64; ++i) {
    const int f = lane + i * 64;            // coalesced, B fully L1-resident (16KB)
    const float d0 = fabsf(a.x - B0[f]);
    const float d1 = fabsf(a.y - B1[f]);
    m = fminf(m, fmaxf(d0, d1));
  }

  // wave min-reduce (64 lanes)
#pragma unroll
  for (int off = 32; off; off >>= 1)
    m = fminf(m, __shfl_xor(m, off));

  // combine the 4 waves of this block (all share the same n: 4 | 512)
  __shared__ float sm[4];
  if (lane == 0) sm[wave] = m;
  __syncthreads();
  if (threadIdx.x == 0) {
    const float t = fmaxf(fmaxf(sm[0], sm[1]), fmaxf(sm[2], sm[3]));
    // t >= 0, so uint bit-pattern compare == float compare; ws pre-zeroed
    atomicMax(ws + n, __float_as_uint(t));
  }
}

__global__ __launch_bounds__(64) void psl_finalize_kernel(
    const unsigned* __restrict__ ws, float* __restrict__ out) {
  const int n = threadIdx.x;
  const float t  = __uint_as_float(ws[n]);
  const float s1 = 1.0f / (1.0f + __expf(-10.0f * t) * 0.0f + expf(-10.0f * t));
  const float s2 = 1.0f / (1.0f + expf(10.0f * t));
  out[n] = s1 * s2;
}

extern "C" void kernel_launch(void* const* d_in, const int* in_sizes, int n_in,
                              void* d_out, int out_size, void* d_ws, size_t ws_size,
                              hipStream_t stream) {
  const float* A = (const float*)d_in[0];   // (64,512,2)
  const float* B = (const float*)d_in[1];   // (1,2,2048)
  float* out     = (float*)d_out;           // (64,1)
  unsigned* ws   = (unsigned*)d_ws;         // 64 slots for max-reduction

  hipMemsetAsync(ws, 0, NN * sizeof(unsigned), stream);

  const int pairs  = NN * LL;               // 32768 (n,l) pairs, 1 wave each
  const int blocks = pairs / 4;             // 4 waves / 256-thread block
  psl_reduce_kernel<<<blocks, 256, 0, stream>>>(A, B, ws);
  psl_finalize_kernel<<<1, 64, 0, stream>>>(ws, out);
}

// Round 2
// 66.803 us; speedup vs baseline: 1.7965x; 1.7965x over previous
//
#include <hip/hip_runtime.h>
#include <hip/hip_bf16.h>

// out[n] = bump( max_l min_f max_c |A[n,l,c] - B[c,f]| ),  bump(x)=sigmoid(10x)*sigmoid(-10x)
// bump is strictly decreasing for x>=0  =>  out[n] = min_blocks bump(t_block)
// N=64, L=512, F=2048.  A:(64,512,2) f32, B:(1,2,2048) f32, out:(64,1) f32.

#define NN 64
#define LL 512
#define FF 2048
#define P  8   // pairs per wave (lanes stripe f)

__global__ __launch_bounds__(256) void psl_reduce_kernel(
    const float* __restrict__ A, const float* __restrict__ B,
    unsigned* __restrict__ out_u) {
  const int wave = __builtin_amdgcn_readfirstlane(threadIdx.x >> 6);
  const int lane = threadIdx.x & 63;
  // block owns 32 consecutive pairs; 16 blocks per n (32*16=512), so n is block-uniform
  const int p_base = blockIdx.x * 32 + wave * P;   // first pair of this wave
  const int n      = blockIdx.x >> 4;

  // A values for this wave's 8 pairs (wave-uniform addresses -> scalar loads)
  float ax[P], ay[P];
#pragma unroll
  for (int i = 0; i < P; ++i) {
    const float2 a = ((const float2*)A)[p_base + i];
    ax[i] = a.x; ay[i] = a.y;
  }

  const float4* __restrict__ B0 = (const float4*)B;         // B[0,0,:]
  const float4* __restrict__ B1 = (const float4*)(B + FF);  // B[0,1,:]

  float m[P];
#pragma unroll
  for (int i = 0; i < P; ++i) m[i] = 3.4e38f;

  // lanes stripe f in float4 chunks: 64 lanes * 4 = 256 f per iter, 8 iters
#pragma unroll
  for (int it = 0; it < FF / 256; ++it) {
    const int idx = it * 64 + lane;
    const float4 b0 = B0[idx];
    const float4 b1 = B1[idx];
#pragma unroll
    for (int i = 0; i < P; ++i) {
      float v;
      v = fmaxf(fabsf(ax[i] - b0.x), fabsf(ay[i] - b1.x)); m[i] = fminf(m[i], v);
      v = fmaxf(fabsf(ax[i] - b0.y), fabsf(ay[i] - b1.y)); m[i] = fminf(m[i], v);
      v = fmaxf(fabsf(ax[i] - b0.z), fabsf(ay[i] - b1.z)); m[i] = fminf(m[i], v);
      v = fmaxf(fabsf(ax[i] - b0.w), fabsf(ay[i] - b1.w)); m[i] = fminf(m[i], v);
    }
  }

  // per-pair min over f (cross-lane), then max over this wave's 8 pairs
  float t = 0.0f;
#pragma unroll
  for (int i = 0; i < P; ++i) {
#pragma unroll
    for (int off = 32; off; off >>= 1)
      m[i] = fminf(m[i], __shfl_xor(m[i], off));
    t = fmaxf(t, m[i]);
  }

  // block max over 4 waves, then bump + atomicMin (uint order == float order, all > 0)
  __shared__ float sm[4];
  if (lane == 0) sm[wave] = t;
  __syncthreads();
  if (threadIdx.x == 0) {
    const float tb = fmaxf(fmaxf(sm[0], sm[1]), fmaxf(sm[2], sm[3]));
    const float g  = (1.0f / (1.0f + expf(-10.0f * tb))) *
                     (1.0f / (1.0f + expf( 10.0f * tb)));
    atomicMin(out_u + n, __float_as_uint(g));
  }
}

extern "C" void kernel_launch(void* const* d_in, const int* in_sizes, int n_in,
                              void* d_out, int out_size, void* d_ws, size_t ws_size,
                              hipStream_t stream) {
  const float* A = (const float*)d_in[0];   // (64,512,2)
  const float* B = (const float*)d_in[1];   // (1,2,2048)
  unsigned* out_u = (unsigned*)d_out;       // (64,1) f32, driven by uint atomicMin

  // 0xFFFFFFFF = uint max -> identity for atomicMin over positive-float bit patterns
  hipMemsetAsync(out_u, 0xFF, NN * sizeof(unsigned), stream);

  const int blocks = (NN * LL) / 32;        // 32 pairs per 256-thread block -> 1024 blocks
  psl_reduce_kernel<<<blocks, 256, 0, stream>>>(A, B, out_u);
}

// Round 3
// 62.606 us; speedup vs baseline: 1.9169x; 1.0670x over previous
//
#include <hip/hip_runtime.h>
#include <hip/hip_bf16.h>

// out[n] = bump( max_l min_f max_c |A[n,l,c] - B[c,f]| ),  bump(x)=sigmoid(10x)*sigmoid(-10x)
// bump strictly decreasing for x>=0  =>  reduce t = max first, bump once at the end.
// Equivalently: per (n,l) point a=(ax,ay), t = L-inf nearest-neighbor distance to the
// 2048 points (B0[f],B1[f]); out[n] = bump(max_l t).
// N=64, L=512, F=2048.  A:(64,512,2) f32, B:(1,2,2048) f32, out:(64,1) f32.

#define NN 64
#define LL 512
#define FF 2048
#define P  8   // pairs per wave (lanes stripe f)

// kernel 1: 1024 blocks x 256 threads; block b owns pairs [32b, 32b+32);
// 16 blocks per n. Writes block max-of-min to ws[b] unconditionally (no init needed).
__global__ __launch_bounds__(256) void psl_reduce_kernel(
    const float* __restrict__ A, const float* __restrict__ B,
    float* __restrict__ ws) {
  const int wave = __builtin_amdgcn_readfirstlane(threadIdx.x >> 6);
  const int lane = threadIdx.x & 63;
  const int p_base = blockIdx.x * 32 + wave * P;   // first pair of this wave

  // A values for this wave's 8 pairs (wave-uniform -> scalar loads)
  float ax[P], ay[P];
#pragma unroll
  for (int i = 0; i < P; ++i) {
    const float2 a = ((const float2*)A)[p_base + i];
    ax[i] = a.x; ay[i] = a.y;
  }

  const float4* __restrict__ B0 = (const float4*)B;         // B[0,0,:]
  const float4* __restrict__ B1 = (const float4*)(B + FF);  // B[0,1,:]

  float m[P];
#pragma unroll
  for (int i = 0; i < P; ++i) m[i] = 3.4e38f;

  // lanes stripe f in float4 chunks: 64 lanes * 4 = 256 f per iter, 8 iters
#pragma unroll
  for (int it = 0; it < FF / 256; ++it) {
    const int idx = it * 64 + lane;
    const float4 b0 = B0[idx];
    const float4 b1 = B1[idx];
#pragma unroll
    for (int i = 0; i < P; ++i) {
      // abs folds into v_max_f32 input modifiers; min-chain folds into v_min3_f32
      const float v0 = fmaxf(fabsf(ax[i] - b0.x), fabsf(ay[i] - b1.x));
      const float v1 = fmaxf(fabsf(ax[i] - b0.y), fabsf(ay[i] - b1.y));
      const float v2 = fmaxf(fabsf(ax[i] - b0.z), fabsf(ay[i] - b1.z));
      const float v3 = fmaxf(fabsf(ax[i] - b0.w), fabsf(ay[i] - b1.w));
      m[i] = fminf(m[i], fminf(fminf(fminf(v0, v1), v2), v3));
    }
  }

  // per-pair min over f (cross-lane), then max over this wave's 8 pairs
  float t = 0.0f;
#pragma unroll
  for (int i = 0; i < P; ++i) {
#pragma unroll
    for (int off = 32; off; off >>= 1)
      m[i] = fminf(m[i], __shfl_xor(m[i], off));
    t = fmaxf(t, m[i]);
  }

  __shared__ float sm[4];
  if (lane == 0) sm[wave] = t;
  __syncthreads();
  if (threadIdx.x == 0)
    ws[blockIdx.x] = fmaxf(fmaxf(sm[0], sm[1]), fmaxf(sm[2], sm[3]));
}

// kernel 2: 1 block x 64 threads; thread n maxes its 16 block results, bumps, stores.
__global__ __launch_bounds__(64) void psl_finalize_kernel(
    const float* __restrict__ ws, float* __restrict__ out) {
  const int n = threadIdx.x;
  float t = 0.0f;
#pragma unroll
  for (int j = 0; j < (LL / 32); ++j)       // 16 blocks per n
    t = fmaxf(t, ws[n * (LL / 32) + j]);
  out[n] = (1.0f / (1.0f + expf(-10.0f * t))) *
           (1.0f / (1.0f + expf( 10.0f * t)));
}

extern "C" void kernel_launch(void* const* d_in, const int* in_sizes, int n_in,
                              void* d_out, int out_size, void* d_ws, size_t ws_size,
                              hipStream_t stream) {
  const float* A = (const float*)d_in[0];   // (64,512,2)
  const float* B = (const float*)d_in[1];   // (1,2,2048)
  float* out     = (float*)d_out;           // (64,1)
  float* ws      = (float*)d_ws;            // 1024 block results

  const int blocks = (NN * LL) / 32;        // 1024
  psl_reduce_kernel<<<blocks, 256, 0, stream>>>(A, B, ws);
  psl_finalize_kernel<<<1, 64, 0, stream>>>(ws, out);
}